// Round 7
// baseline (218.551 us; speedup 1.0000x reference)
//
#include <hip/hip_runtime.h>
#include <cstdint>
#include <cstddef>

// DigitCapsule dynamic routing, fp32.
// x[256,1152,8], W[1152,10,16,8], out v[256,10,16].
// Design: lane = q*16 + d. d-reductions (logits, squash) are 16-lane
// xor-butterflies via ds_swizzle -> no barriers in capsV.
// vsum trick: logits at round r = votes . (v0+...+v_{r-1}).
// R7: keep R6's 2-b/thread (FMA:load fix, proven -28%), restore TLP:
//   - CA=6 -> 192 chunks, grid 1536 blocks = 6 waves/SIMD from the grid
//     (R6's 768 blocks gave only 3, and occupancy measured 22%).
//   - waves_per_eu(4,5): R6's (3,4) CAPPED residency at 4; (4,5) allows 5
//     while keeping the VGPR budget (102) above our measured 84 so the
//     allocator doesn't re-sink the load clusters.
constexpr int Bn = 256, In = 1152, Pn = 8, Jn = 10, Dn = 16;
constexpr int CA = 6, NCH = In / CA;  // 192 chunks

template <int MASK>
__device__ __forceinline__ float swzadd(float v) {
  const int s = __builtin_amdgcn_ds_swizzle(__float_as_int(v), MASK);
  return v + __int_as_float(s);
}

// Sum over the 16 lanes of each row (lane&15 = d); every lane gets the sum.
// ds_swizzle BitMode: offset = xor<<10 | or<<5 | and(0x1F). LDS pipe.
__device__ __forceinline__ float rowsum16(float v) {
  v = swzadd<0x041F>(v);  // xor 1
  v = swzadd<0x081F>(v);  // xor 2
  v = swzadd<0x101F>(v);  // xor 4
  v = swzadd<0x201F>(v);  // xor 8
  return v;
}

__device__ __forceinline__ float dot8(const float4 a0, const float4 a1,
                                      const float4 b0, const float4 b1) {
  float s = a0.x * b0.x;
  s = fmaf(a0.y, b0.y, s); s = fmaf(a0.z, b0.z, s); s = fmaf(a0.w, b0.w, s);
  s = fmaf(a1.x, b1.x, s); s = fmaf(a1.y, b1.y, s); s = fmaf(a1.z, b1.z, s);
  s = fmaf(a1.w, b1.w, s);
  return s;
}

// capsV: one routing round's weighted vote sum over an i-chunk, 2 b's/thread.
// thread: d = t&15, q = t>>4; b0 = blockIdx.y*32 + q, b1 = b0 + 16.
// block = (chunk, b-group of 32). Per (i,j): one 32B W load -> two dots.
// MODE 0: softmax of zero logits = 0.1 exactly -> raw vote sum * 0.1.
template <int MODE>
__global__ __launch_bounds__(256)
__attribute__((amdgpu_waves_per_eu(4, 5)))
void capsV(const float* __restrict__ x, const float* __restrict__ w,
           const float* __restrict__ vsumT, float* __restrict__ spart) {
  const int t = threadIdx.x;
  const int d = t & 15, q = t >> 4;
  const int ch = blockIdx.x;
  const int b0 = blockIdx.y * 32 + q, b1 = b0 + 16;

  float vs0[Jn], vs1[Jn], acc0[Jn], acc1[Jn];
  #pragma unroll
  for (int j = 0; j < Jn; ++j) {
    acc0[j] = 0.f; acc1[j] = 0.f;
    if (MODE) {
      vs0[j] = vsumT[((size_t)j * Bn + b0) * Dn + d];
      vs1[j] = vsumT[((size_t)j * Bn + b1) * Dn + d];
    }
  }

  const int i0 = ch * CA;
  const float* xp0 = x + ((size_t)b0 * In + i0) * Pn;
  const float* xp1 = x + ((size_t)b1 * In + i0) * Pn;
  const float* wp = w + (((size_t)i0 * Jn) * Dn + d) * Pn;

  for (int ii = 0; ii < CA; ++ii) {
    const float4 xa0 = reinterpret_cast<const float4*>(xp0)[0];
    const float4 xa1 = reinterpret_cast<const float4*>(xp0)[1];
    const float4 xb0 = reinterpret_cast<const float4*>(xp1)[0];
    const float4 xb1 = reinterpret_cast<const float4*>(xp1)[1];

    float vt0[Jn], vt1[Jn];
    #pragma unroll
    for (int j = 0; j < Jn; ++j) {
      const float4* wj =
          reinterpret_cast<const float4*>(wp + (size_t)j * (Dn * Pn));
      const float4 w0 = wj[0], w1 = wj[1];
      vt0[j] = dot8(w0, w1, xa0, xa1);
      vt1[j] = dot8(w0, w1, xb0, xb1);
    }

    if (MODE) {
      float l0[Jn], l1[Jn];
      #pragma unroll
      for (int j = 0; j < Jn; ++j) {
        l0[j] = rowsum16(vt0[j] * vs0[j]);
        l1[j] = rowsum16(vt1[j] * vs1[j]);
      }
      // softmax over j; logits are O(0.1) so no max-subtraction needed.
      float sa = 0.f, sb = 0.f;
      #pragma unroll
      for (int j = 0; j < Jn; ++j) {
        l0[j] = __expf(l0[j]); sa += l0[j];
        l1[j] = __expf(l1[j]); sb += l1[j];
      }
      const float ia = __builtin_amdgcn_rcpf(sa);
      const float ib = __builtin_amdgcn_rcpf(sb);
      #pragma unroll
      for (int j = 0; j < Jn; ++j) {
        acc0[j] = fmaf(l0[j] * ia, vt0[j], acc0[j]);
        acc1[j] = fmaf(l1[j] * ib, vt1[j], acc1[j]);
      }
    } else {
      #pragma unroll
      for (int j = 0; j < Jn; ++j) { acc0[j] += vt0[j]; acc1[j] += vt1[j]; }
    }

    xp0 += Pn;
    xp1 += Pn;
    wp += (size_t)Jn * Dn * Pn;
  }

  const float cs = MODE ? 1.f : 0.1f;
  #pragma unroll
  for (int j = 0; j < Jn; ++j) {
    spart[(((size_t)ch * Jn + j) * Bn + b0) * Dn + d] = acc0[j] * cs;
    spart[(((size_t)ch * Jn + j) * Bn + b1) * Dn + d] = acc1[j] * cs;
  }
}

// capsF: reduce 192 chunk-partials, squash. 1024 threads: 4 chunk-groups
// (cg = t>>8) each privately sum 48 chunks; LDS combine across cg; squash
// norm via rowsum16 in the t<256 tail. block = (j, b-group of 16).
// MODE 0: vsumT = v ; MODE 1: vsumT += v ; MODE 2: out[b][j][d] = v.
template <int MODE>
__global__ __launch_bounds__(1024) void capsF(
    const float* __restrict__ spart, float* __restrict__ vsumT,
    float* __restrict__ out) {
  __shared__ float red[4][16][16];
  const int t = threadIdx.x;
  const int cg = t >> 8, r = t & 255, g = r >> 4, d = r & 15;
  const int j = blockIdx.x, b = blockIdx.y * 16 + g;

  const size_t cstride = (size_t)Jn * Bn * Dn;  // one chunk, in floats
  const size_t cstep = 4 * cstride;             // stride between my chunks
  const float* sp = spart + (((size_t)cg * Jn + j) * Bn + b) * Dn + d;
  float s0 = 0.f, s1 = 0.f;
  #pragma unroll 4
  for (int k = 0; k < NCH / 4; k += 2) {
    s0 += sp[0];
    s1 += sp[cstep];
    sp += 2 * cstep;
  }
  red[cg][g][d] = s0 + s1;
  __syncthreads();
  if (t < 256) {
    const float z = red[0][g][d] + red[1][g][d] + red[2][g][d] + red[3][g][d];
    const float n2 = rowsum16(z * z);
    const float sc = n2 / (1.f + n2) / sqrtf(n2 + 1e-7f);
    const float v = z * sc;
    if (MODE == 2) {
      out[((size_t)b * Jn + j) * Dn + d] = v;
    } else if (MODE == 1) {
      vsumT[((size_t)j * Bn + b) * Dn + d] += v;
    } else {
      vsumT[((size_t)j * Bn + b) * Dn + d] = v;
    }
  }
}

extern "C" void kernel_launch(void* const* d_in, const int* in_sizes, int n_in,
                              void* d_out, int out_size, void* d_ws, size_t ws_size,
                              hipStream_t stream) {
  const float* x = (const float*)d_in[0];  // [256,1152,8]
  const float* w = (const float*)d_in[1];  // [1152,10,16,8]
  float* vsumT = (float*)d_ws;                      // [J][B][D]   0.16 MB
  float* spart = vsumT + (size_t)Jn * Bn * Dn;      // [NCH][J][B][D] 31.5 MB
  float* out = (float*)d_out;                       // [256,10,16]

  const dim3 gV(NCH, Bn / 32), gF(Jn, Bn / 16);

  capsV<0><<<gV, 256, 0, stream>>>(x, w, nullptr, spart);
  capsF<0><<<gF, 1024, 0, stream>>>(spart, vsumT, out);   // vsum = v0

  capsV<1><<<gV, 256, 0, stream>>>(x, w, vsumT, spart);   // round 1
  capsF<1><<<gF, 1024, 0, stream>>>(spart, vsumT, out);   // vsum += v1

  capsV<1><<<gV, 256, 0, stream>>>(x, w, vsumT, spart);   // round 2
  capsF<2><<<gF, 1024, 0, stream>>>(spart, vsumT, out);   // out = v2
}

// Round 8
// 199.083 us; speedup vs baseline: 1.0978x; 1.0978x over previous
//
#include <hip/hip_runtime.h>
#include <cstdint>
#include <cstddef>

// DigitCapsule dynamic routing, fp32.
// x[256,1152,8], W[1152,10,16,8], out v[256,10,16].
// Design: lane = q*16 + d. d-reductions (logits, squash) are 16-lane
// xor-butterflies via ds_swizzle -> no barriers in capsV.
// vsum trick: logits at round r = votes . (v0+...+v_{r-1}).
// R8 = R6 (proven best: 2-b/thread, waves_per_eu(3,4) -> VGPR 84) with ONE
// change: CA 12->8 (144 chunks x 8 b-groups = 1152 blocks = 4.5 blocks/CU)
// to fix the grid-supply TLP starvation R6's counters showed (Occ 22% with
// a 4-wave cap and only 3 blocks/CU available).
// R7's waves_per_eu(4,5) regressed (VGPR 64 = load re-sinking) - reverted.
constexpr int Bn = 256, In = 1152, Pn = 8, Jn = 10, Dn = 16;
constexpr int CA = 8, NCH = In / CA;  // 144 chunks

template <int MASK>
__device__ __forceinline__ float swzadd(float v) {
  const int s = __builtin_amdgcn_ds_swizzle(__float_as_int(v), MASK);
  return v + __int_as_float(s);
}

// Sum over the 16 lanes of each row (lane&15 = d); every lane gets the sum.
// ds_swizzle BitMode: offset = xor<<10 | or<<5 | and(0x1F). LDS pipe.
__device__ __forceinline__ float rowsum16(float v) {
  v = swzadd<0x041F>(v);  // xor 1
  v = swzadd<0x081F>(v);  // xor 2
  v = swzadd<0x101F>(v);  // xor 4
  v = swzadd<0x201F>(v);  // xor 8
  return v;
}

__device__ __forceinline__ float dot8(const float4 a0, const float4 a1,
                                      const float4 b0, const float4 b1) {
  float s = a0.x * b0.x;
  s = fmaf(a0.y, b0.y, s); s = fmaf(a0.z, b0.z, s); s = fmaf(a0.w, b0.w, s);
  s = fmaf(a1.x, b1.x, s); s = fmaf(a1.y, b1.y, s); s = fmaf(a1.z, b1.z, s);
  s = fmaf(a1.w, b1.w, s);
  return s;
}

// capsV: one routing round's weighted vote sum over an i-chunk, 2 b's/thread.
// thread: d = t&15, q = t>>4; b0 = blockIdx.y*32 + q, b1 = b0 + 16.
// block = (chunk, b-group of 32). Per (i,j): one 32B W load -> two dots.
// MODE 0: softmax of zero logits = 0.1 exactly -> raw vote sum * 0.1.
template <int MODE>
__global__ __launch_bounds__(256)
__attribute__((amdgpu_waves_per_eu(3, 4)))
void capsV(const float* __restrict__ x, const float* __restrict__ w,
           const float* __restrict__ vsumT, float* __restrict__ spart) {
  const int t = threadIdx.x;
  const int d = t & 15, q = t >> 4;
  const int ch = blockIdx.x;
  const int b0 = blockIdx.y * 32 + q, b1 = b0 + 16;

  float vs0[Jn], vs1[Jn], acc0[Jn], acc1[Jn];
  #pragma unroll
  for (int j = 0; j < Jn; ++j) {
    acc0[j] = 0.f; acc1[j] = 0.f;
    if (MODE) {
      vs0[j] = vsumT[((size_t)j * Bn + b0) * Dn + d];
      vs1[j] = vsumT[((size_t)j * Bn + b1) * Dn + d];
    }
  }

  const int i0 = ch * CA;
  const float* xp0 = x + ((size_t)b0 * In + i0) * Pn;
  const float* xp1 = x + ((size_t)b1 * In + i0) * Pn;
  const float* wp = w + (((size_t)i0 * Jn) * Dn + d) * Pn;

  for (int ii = 0; ii < CA; ++ii) {
    const float4 xa0 = reinterpret_cast<const float4*>(xp0)[0];
    const float4 xa1 = reinterpret_cast<const float4*>(xp0)[1];
    const float4 xb0 = reinterpret_cast<const float4*>(xp1)[0];
    const float4 xb1 = reinterpret_cast<const float4*>(xp1)[1];

    float vt0[Jn], vt1[Jn];
    #pragma unroll
    for (int j = 0; j < Jn; ++j) {
      const float4* wj =
          reinterpret_cast<const float4*>(wp + (size_t)j * (Dn * Pn));
      const float4 w0 = wj[0], w1 = wj[1];
      vt0[j] = dot8(w0, w1, xa0, xa1);
      vt1[j] = dot8(w0, w1, xb0, xb1);
    }

    if (MODE) {
      float l0[Jn], l1[Jn];
      #pragma unroll
      for (int j = 0; j < Jn; ++j) {
        l0[j] = rowsum16(vt0[j] * vs0[j]);
        l1[j] = rowsum16(vt1[j] * vs1[j]);
      }
      // softmax over j; logits are O(0.1) so no max-subtraction needed.
      float sa = 0.f, sb = 0.f;
      #pragma unroll
      for (int j = 0; j < Jn; ++j) {
        l0[j] = __expf(l0[j]); sa += l0[j];
        l1[j] = __expf(l1[j]); sb += l1[j];
      }
      const float ia = __builtin_amdgcn_rcpf(sa);
      const float ib = __builtin_amdgcn_rcpf(sb);
      #pragma unroll
      for (int j = 0; j < Jn; ++j) {
        acc0[j] = fmaf(l0[j] * ia, vt0[j], acc0[j]);
        acc1[j] = fmaf(l1[j] * ib, vt1[j], acc1[j]);
      }
    } else {
      #pragma unroll
      for (int j = 0; j < Jn; ++j) { acc0[j] += vt0[j]; acc1[j] += vt1[j]; }
    }

    xp0 += Pn;
    xp1 += Pn;
    wp += (size_t)Jn * Dn * Pn;
  }

  const float cs = MODE ? 1.f : 0.1f;
  #pragma unroll
  for (int j = 0; j < Jn; ++j) {
    spart[(((size_t)ch * Jn + j) * Bn + b0) * Dn + d] = acc0[j] * cs;
    spart[(((size_t)ch * Jn + j) * Bn + b1) * Dn + d] = acc1[j] * cs;
  }
}

// capsF: reduce 144 chunk-partials, squash. 1024 threads: 4 chunk-groups
// (cg = t>>8) each privately sum 36 chunks; LDS combine across cg; squash
// norm via rowsum16 in the t<256 tail. block = (j, b-group of 16).
// MODE 0: vsumT = v ; MODE 1: vsumT += v ; MODE 2: out[b][j][d] = v.
template <int MODE>
__global__ __launch_bounds__(1024) void capsF(
    const float* __restrict__ spart, float* __restrict__ vsumT,
    float* __restrict__ out) {
  __shared__ float red[4][16][16];
  const int t = threadIdx.x;
  const int cg = t >> 8, r = t & 255, g = r >> 4, d = r & 15;
  const int j = blockIdx.x, b = blockIdx.y * 16 + g;

  const size_t cstride = (size_t)Jn * Bn * Dn;  // one chunk, in floats
  const size_t cstep = 4 * cstride;             // stride between my chunks
  const float* sp = spart + (((size_t)cg * Jn + j) * Bn + b) * Dn + d;
  float s0 = 0.f, s1 = 0.f;
  #pragma unroll 4
  for (int k = 0; k < NCH / 4; k += 2) {
    s0 += sp[0];
    s1 += sp[cstep];
    sp += 2 * cstep;
  }
  red[cg][g][d] = s0 + s1;
  __syncthreads();
  if (t < 256) {
    const float z = red[0][g][d] + red[1][g][d] + red[2][g][d] + red[3][g][d];
    const float n2 = rowsum16(z * z);
    const float sc = n2 / (1.f + n2) / sqrtf(n2 + 1e-7f);
    const float v = z * sc;
    if (MODE == 2) {
      out[((size_t)b * Jn + j) * Dn + d] = v;
    } else if (MODE == 1) {
      vsumT[((size_t)j * Bn + b) * Dn + d] += v;
    } else {
      vsumT[((size_t)j * Bn + b) * Dn + d] = v;
    }
  }
}

extern "C" void kernel_launch(void* const* d_in, const int* in_sizes, int n_in,
                              void* d_out, int out_size, void* d_ws, size_t ws_size,
                              hipStream_t stream) {
  const float* x = (const float*)d_in[0];  // [256,1152,8]
  const float* w = (const float*)d_in[1];  // [1152,10,16,8]
  float* vsumT = (float*)d_ws;                      // [J][B][D]   0.16 MB
  float* spart = vsumT + (size_t)Jn * Bn * Dn;      // [NCH][J][B][D] 23.6 MB
  float* out = (float*)d_out;                       // [256,10,16]

  const dim3 gV(NCH, Bn / 32), gF(Jn, Bn / 16);

  capsV<0><<<gV, 256, 0, stream>>>(x, w, nullptr, spart);
  capsF<0><<<gF, 1024, 0, stream>>>(spart, vsumT, out);   // vsum = v0

  capsV<1><<<gV, 256, 0, stream>>>(x, w, vsumT, spart);   // round 1
  capsF<1><<<gF, 1024, 0, stream>>>(spart, vsumT, out);   // vsum += v1

  capsV<1><<<gV, 256, 0, stream>>>(x, w, vsumT, spart);   // round 2
  capsF<2><<<gF, 1024, 0, stream>>>(spart, vsumT, out);   // out = v2
}